// Round 9
// baseline (103.353 us; speedup 1.0000x reference)
//
#include <hip/hip_runtime.h>
#include <math.h>

#define Bb   2
#define Hh   56
#define Ww   56
#define Cc   256
#define NHh  8
#define HDd  32
#define KK   7
#define HWsz (Hh*Ww)
#define Mtot (Bb*Hh*Ww)   // 6272

typedef __bf16 bf16x8 __attribute__((ext_vector_type(8)));
typedef __bf16 bf16x4 __attribute__((ext_vector_type(4)));
typedef float  f32x4  __attribute__((ext_vector_type(4)));

// One-shot fp32 -> bf16 conversion of x, w_qk, w_v, w_proj.
__global__ __launch_bounds__(256) void prep_bf16(
    const float* __restrict__ x, const float* __restrict__ wqk,
    const float* __restrict__ wv, const float* __restrict__ wp,
    __bf16* __restrict__ xb, __bf16* __restrict__ wallb, __bf16* __restrict__ wpb)
{
    const int t = blockIdx.x * 256 + threadIdx.x;   // 912*256 = 233472 chunks
    const float* src; __bf16* dst; int off;
    if (t < 200704)      { src = x;   dst = xb;             off = t; }
    else if (t < 217088) { src = wqk; dst = wallb;          off = t - 200704; }
    else if (t < 225280) { src = wv;  dst = wallb + 131072; off = t - 217088; }
    else                 { src = wp;  dst = wpb;            off = t - 225280; }
    const int e = off * 8;
    float4 a = *(const float4*)(src + e);
    float4 b = *(const float4*)(src + e + 4);
    bf16x8 o = { (__bf16)a.x, (__bf16)a.y, (__bf16)a.z, (__bf16)a.w,
                 (__bf16)b.x, (__bf16)b.y, (__bf16)b.z, (__bf16)b.w };
    *(bf16x8*)(dst + e) = o;
}

// bf16 GEMM: C[m,n] = sum_k A[m,k] * W[n,k].  Kdim = 256 fixed.
// 128x64 tile, BK=64, 256 threads (4 waves); wave w owns rows [w*32, w*32+32).
// Frag-ordered LDS: 512-elem blocks [16m x 32k]; A blk = ks*8+sub (16 blocks),
// B blk = ks*4+sub (8 blocks). 16B-chunk XOR swizzle (c ^ (row&3)).
// QKV=true: Out bf16 stride 768, scale cols<256. QKV=false: fp32 + bias, stride 256.
template<bool QKV>
__global__ __launch_bounds__(256) void gemm128(
    const __bf16* __restrict__ A, const __bf16* __restrict__ W,
    __bf16* __restrict__ OutB, float* __restrict__ OutF,
    const float* __restrict__ bias, int N, float scale)
{
    __shared__ __bf16 As[8192];   // 128 x 64
    __shared__ __bf16 Bs[4096];   // 64 x 64

    const int tid = threadIdx.x;
    const int m0  = blockIdx.y * 128;
    const int n0  = blockIdx.x * 64;

    // A staging: thread t -> row_a = t>>1, ks half = t&1, all 4 chunks of 8
    const int row_a = tid >> 1;
    const int ksA   = tid & 1;
    const __bf16* aptr = A + (size_t)(m0 + row_a) * 256 + ksA * 32;
    const int blkA  = (ksA * 8 + (row_a >> 4)) * 512 + (row_a & 15) * 32;
    const int swzA  = row_a & 3;

    // B staging: thread t -> row_b = t>>2, pr = t&3 -> (ks half, chunk pair)
    const int row_b = tid >> 2;
    const int pr    = tid & 3;
    const int ksB   = pr >> 1;
    const int c0B   = (pr & 1) * 2;
    const __bf16* bptr = W + (size_t)(n0 + row_b) * 256 + ksB * 32 + c0B * 8;  // FIX: + c0B*8
    const int blkB  = (ksB * 4 + (row_b >> 4)) * 512 + (row_b & 15) * 32;
    const int swzB  = row_b & 3;

    const int w    = tid >> 6;
    const int lane = tid & 63;
    const int fr_row = lane & 15;
    const int fr_c   = lane >> 4;
    const int fr_off = fr_row * 32 + ((fr_c ^ (fr_row & 3)) * 8);

    f32x4 acc[2][4] = {};

    for (int k0 = 0; k0 < 256; k0 += 64) {
        bf16x8 a0 = *(const bf16x8*)(aptr + k0);
        bf16x8 a1 = *(const bf16x8*)(aptr + k0 + 8);
        bf16x8 a2 = *(const bf16x8*)(aptr + k0 + 16);
        bf16x8 a3 = *(const bf16x8*)(aptr + k0 + 24);
        bf16x8 b0 = *(const bf16x8*)(bptr + k0);
        bf16x8 b1 = *(const bf16x8*)(bptr + k0 + 8);
        __syncthreads();   // previous iter's frag reads done
        *(bf16x8*)&As[blkA + ((0 ^ swzA) * 8)] = a0;
        *(bf16x8*)&As[blkA + ((1 ^ swzA) * 8)] = a1;
        *(bf16x8*)&As[blkA + ((2 ^ swzA) * 8)] = a2;
        *(bf16x8*)&As[blkA + ((3 ^ swzA) * 8)] = a3;
        *(bf16x8*)&Bs[blkB + ((c0B ^ swzB) * 8)] = b0;
        *(bf16x8*)&Bs[blkB + (((c0B + 1) ^ swzB) * 8)] = b1;
        __syncthreads();
        #pragma unroll
        for (int ks = 0; ks < 2; ++ks) {
            bf16x8 af0 = *(const bf16x8*)&As[(ks * 8 + 2 * w + 0) * 512 + fr_off];
            bf16x8 af1 = *(const bf16x8*)&As[(ks * 8 + 2 * w + 1) * 512 + fr_off];
            #pragma unroll
            for (int n = 0; n < 4; ++n) {
                bf16x8 bfr = *(const bf16x8*)&Bs[(ks * 4 + n) * 512 + fr_off];
                acc[0][n] = __builtin_amdgcn_mfma_f32_16x16x32_bf16(af0, bfr, acc[0][n], 0, 0, 0);
                acc[1][n] = __builtin_amdgcn_mfma_f32_16x16x32_bf16(af1, bfr, acc[1][n], 0, 0, 0);
            }
        }
    }

    // epilogue: col = lane&15 (+n*16+n0), row = m0 + w*32 + i*16 + fr_c*4 + r
    #pragma unroll
    for (int n = 0; n < 4; ++n) {
        const int gcol = n0 + n * 16 + fr_row;
        if (QKV) {
            const float sc_ = (gcol < 256) ? scale : 1.f;
            #pragma unroll
            for (int i = 0; i < 2; ++i)
                #pragma unroll
                for (int r = 0; r < 4; ++r) {
                    const int grow = m0 + w * 32 + i * 16 + fr_c * 4 + r;
                    OutB[(size_t)grow * 768 + gcol] = (__bf16)(acc[i][n][r] * sc_);
                }
        } else {
            const float bs_ = bias[gcol];
            #pragma unroll
            for (int i = 0; i < 2; ++i)
                #pragma unroll
                for (int r = 0; r < 4; ++r) {
                    const int grow = m0 + w * 32 + i * 16 + fr_c * 4 + r;
                    OutF[(size_t)grow * 256 + gcol] = acc[i][n][r] + bs_;
                }
        }
    }
}

// Neighborhood attention, 8x4 query tile per (b, head). 256 threads.
__global__ __launch_bounds__(256, 5) void nattn_84(
    const __bf16* __restrict__ qkv, __bf16* __restrict__ attn_out,
    float* __restrict__ attn_glob)
{
    __shared__ __align__(16) __bf16 Ks[140 * 40];   // K then V (bf16)
    __shared__ float Ss[32 * 49];                   // probs

    const int bx   = blockIdx.x;
    const int head = bx & 7;
    int t = bx >> 3;
    const int tj = t % 14; t /= 14;
    const int ti = t % 7;
    const int b  = t / 7;
    const int tid = threadIdx.x;

    int base_h = ti * 8 - 3; if (base_h < 0) base_h = 0; if (base_h > Hh - 14) base_h = Hh - 14;
    int base_w = tj * 4 - 3; if (base_w < 0) base_w = 0; if (base_w > Ww - 10) base_w = Ww - 10;

    const int pixb = b * HWsz;
    const int hoff = head * 32;

    #pragma unroll
    for (int it = 0; it < 3; ++it) {
        const int idx = tid + it * 256;
        if (idx < 560) {
            const int p = idx >> 2, c = idx & 3;
            const int pix = pixb + (base_h + p / 10) * Ww + base_w + p % 10;
            *(bf16x8*)&Ks[p * 40 + c * 8] =
                *(const bf16x8*)&qkv[(size_t)pix * 768 + 256 + hoff + c * 8];
        }
    }

    const int q  = tid >> 3;
    const int r  = tid & 7;
    const int qi = ti * 8 + (q >> 2);
    const int qj = tj * 4 + (q & 3);

    float qreg[32];
    {
        const __bf16* qp = &qkv[(size_t)(pixb + qi * Ww + qj) * 768 + hoff];
        #pragma unroll
        for (int c = 0; c < 4; ++c) {
            bf16x8 qv = *(const bf16x8*)(qp + c * 8);
            #pragma unroll
            for (int j = 0; j < 8; ++j) qreg[c * 8 + j] = (float)qv[j];
        }
    }

    bf16x8 vreg[3];
    #pragma unroll
    for (int it = 0; it < 3; ++it) {
        const int idx = tid + it * 256;
        if (idx < 560) {
            const int p = idx >> 2, c = idx & 3;
            const int pix = pixb + (base_h + p / 10) * Ww + base_w + p % 10;
            vreg[it] = *(const bf16x8*)&qkv[(size_t)pix * 768 + 512 + hoff + c * 8];
        }
    }
    __syncthreads();

    int ih0 = qi - 3; if (ih0 < 0) ih0 = 0; if (ih0 > Hh - 7) ih0 = Hh - 7;
    int iw0 = qj - 3; if (iw0 < 0) iw0 = 0; if (iw0 > Ww - 7) iw0 = Ww - 7;
    const int lh0 = ih0 - base_h, lw0 = iw0 - base_w;

    float sc[7];
    float mx = -1e30f;
    #pragma unroll
    for (int tt = 0; tt < 7; ++tt) {
        const int k = r + 8 * tt;
        if (k < 49) {
            const int krow = (lh0 + k / 7) * 10 + lw0 + k % 7;
            const __bf16* kp = &Ks[krow * 40];
            float acc = 0.f;
            #pragma unroll
            for (int c = 0; c < 4; ++c) {
                bf16x8 kv = *(const bf16x8*)(kp + c * 8);
                #pragma unroll
                for (int j = 0; j < 8; ++j)
                    acc += qreg[c * 8 + j] * (float)kv[j];
            }
            sc[tt] = acc;
            mx = fmaxf(mx, acc);
        }
    }
    mx = fmaxf(mx, __shfl_xor(mx, 1));
    mx = fmaxf(mx, __shfl_xor(mx, 2));
    mx = fmaxf(mx, __shfl_xor(mx, 4));
    float sum = 0.f;
    #pragma unroll
    for (int tt = 0; tt < 7; ++tt) {
        const int k = r + 8 * tt;
        if (k < 49) { sc[tt] = __expf(sc[tt] - mx); sum += sc[tt]; }
    }
    sum += __shfl_xor(sum, 1);
    sum += __shfl_xor(sum, 2);
    sum += __shfl_xor(sum, 4);
    const float inv = 1.f / sum;
    #pragma unroll
    for (int tt = 0; tt < 7; ++tt) {
        const int k = r + 8 * tt;
        if (k < 49) Ss[q * 49 + k] = sc[tt] * inv;
    }
    __syncthreads();

    #pragma unroll
    for (int it = 0; it < 3; ++it) {
        const int idx = tid + it * 256;
        if (idx < 560) {
            const int p = idx >> 2, c = idx & 3;
            *(bf16x8*)&Ks[p * 40 + c * 8] = vreg[it];
        }
    }
    const size_t agbase = (size_t)(b * NHh + head) * HWsz;
    for (int idx = tid; idx < 32 * 49; idx += 256) {
        const int qq = idx / 49, k = idx - qq * 49;
        attn_glob[(agbase + (ti * 8 + (qq >> 2)) * Ww + tj * 4 + (qq & 3)) * 49 + k]
            = Ss[qq * 49 + k];
    }
    __syncthreads();

    const int rc  = r & 3;
    const int par = r >> 2;
    float a[8] = {};
    #pragma unroll
    for (int tt = 0; tt < 25; ++tt) {
        const int k = par + 2 * tt;
        if (k < 49) {
            const float pr = Ss[q * 49 + k];
            const int vrow = (lh0 + k / 7) * 10 + lw0 + k % 7;
            bf16x8 v8 = *(const bf16x8*)&Ks[vrow * 40 + rc * 8];
            #pragma unroll
            for (int j = 0; j < 8; ++j)
                a[j] += pr * (float)v8[j];
        }
    }
    #pragma unroll
    for (int j = 0; j < 8; ++j) a[j] += __shfl_xor(a[j], 4);

    bf16x4 o = { (__bf16)a[par * 4 + 0], (__bf16)a[par * 4 + 1],
                 (__bf16)a[par * 4 + 2], (__bf16)a[par * 4 + 3] };
    *(bf16x4*)(attn_out + (size_t)(pixb + qi * Ww + qj) * 256 + hoff + rc * 8 + par * 4) = o;
}

extern "C" void kernel_launch(void* const* d_in, const int* in_sizes, int n_in,
                              void* d_out, int out_size, void* d_ws, size_t ws_size,
                              hipStream_t stream)
{
    const float* x      = (const float*)d_in[0];
    const float* w_qk   = (const float*)d_in[1];
    const float* w_v    = (const float*)d_in[2];
    const float* w_proj = (const float*)d_in[3];
    const float* b_proj = (const float*)d_in[4];

    float* out       = (float*)d_out;                    // chunk 0: (B,H,W,C)
    float* attn_glob = out + (size_t)Mtot * Cc;          // chunk 1: (B,NH,H,W,49)

    __bf16* xb      = (__bf16*)d_ws;                     // M x 256
    __bf16* wallb   = xb + (size_t)Mtot * 256;           // 768 x 256 (qk | v)
    __bf16* wpb     = wallb + 768 * 256;                 // 256 x 256
    __bf16* qkv_ws  = wpb + 256 * 256;                   // M x 768 (q|k|v)
    __bf16* attn_ws = qkv_ws + (size_t)Mtot * 768;       // M x 256

    const float scale = 0.17677669529663687f;            // HD^-0.5

    prep_bf16<<<912, 256, 0, stream>>>(x, w_qk, w_v, w_proj, xb, wallb, wpb);

    gemm128<true><<<dim3(768 / 64, Mtot / 128), 256, 0, stream>>>(
        xb, wallb, qkv_ws, nullptr, nullptr, 768, scale);

    nattn_84<<<Bb * 7 * 14 * NHh, 256, 0, stream>>>(qkv_ws, attn_ws, attn_glob);

    gemm128<false><<<dim3(256 / 64, Mtot / 128), 256, 0, stream>>>(
        attn_ws, wpb, nullptr, out, b_proj, 256, 1.f);
}